// Round 1
// baseline (1653.300 us; speedup 1.0000x reference)
//
#include <hip/hip_runtime.h>

#define M_TOT 8192
#define N_TOT 11008
#define K_TOT 4096

#define BM 128
#define BN 128
#define BK 64

typedef _Float16 v8h __attribute__((ext_vector_type(8)));
typedef float v4f __attribute__((ext_vector_type(4)));

// ---------------------------------------------------------------------------
// Convert input fp32 -> fp16 (each thread: 8 elements)
// ---------------------------------------------------------------------------
__global__ void cvt_a_kernel(const float* __restrict__ in, _Float16* __restrict__ out) {
    int idx = blockIdx.x * blockDim.x + threadIdx.x;
    float4 f0 = ((const float4*)in)[idx * 2];
    float4 f1 = ((const float4*)in)[idx * 2 + 1];
    v8h h;
    h[0] = (_Float16)f0.x; h[1] = (_Float16)f0.y;
    h[2] = (_Float16)f0.z; h[3] = (_Float16)f0.w;
    h[4] = (_Float16)f1.x; h[5] = (_Float16)f1.y;
    h[6] = (_Float16)f1.z; h[7] = (_Float16)f1.w;
    ((v8h*)out)[idx] = h;
}

// ---------------------------------------------------------------------------
// Convert qweight int32 (int8-valued, exact in fp16) -> fp16
// ---------------------------------------------------------------------------
__global__ void cvt_w_kernel(const int* __restrict__ q, _Float16* __restrict__ out) {
    int idx = blockIdx.x * blockDim.x + threadIdx.x;
    int4 q0 = ((const int4*)q)[idx * 2];
    int4 q1 = ((const int4*)q)[idx * 2 + 1];
    v8h h;
    h[0] = (_Float16)q0.x; h[1] = (_Float16)q0.y;
    h[2] = (_Float16)q0.z; h[3] = (_Float16)q0.w;
    h[4] = (_Float16)q1.x; h[5] = (_Float16)q1.y;
    h[6] = (_Float16)q1.z; h[7] = (_Float16)q1.w;
    ((v8h*)out)[idx] = h;
}

// ---------------------------------------------------------------------------
// 16B async global->LDS copy (dest = wave-uniform base + lane*16)
// ---------------------------------------------------------------------------
__device__ static inline void load_lds16(const void* g, void* l) {
    __builtin_amdgcn_global_load_lds(
        (const __attribute__((address_space(1))) unsigned int*)g,
        (__attribute__((address_space(3))) unsigned int*)l,
        16, 0, 0);
}

// ---------------------------------------------------------------------------
// GEMM: C[m,n] = scale[n] * sum_k A16[m,k]*W16[n,k] + bias[n]
// A16: [M,K] fp16 row-major; W16: [N,K] fp16 row-major (i.e. B^T layout).
// 128x128 tile, BK=64, 256 threads (4 waves), each wave does a 64x64 quadrant
// as 4x4 grid of 16x16x32 f16 MFMAs.
// ---------------------------------------------------------------------------
__global__ __launch_bounds__(256) void qgemm_kernel(
    const _Float16* __restrict__ A,
    const _Float16* __restrict__ Bw,
    const float* __restrict__ w_scale,
    const float* __restrict__ bias_g,
    float* __restrict__ C)
{
    __shared__ __align__(16) _Float16 Als[BM * BK];   // [row][k], 16 KB
    __shared__ __align__(16) _Float16 Bls[BN * BK];   // [col][k], 16 KB

    const int tid  = threadIdx.x;
    const int lane = tid & 63;
    const int wave = tid >> 6;

    const int brow = blockIdx.y * BM;
    const int bcol = blockIdx.x * BN;

    // Staging addressing: per j in 0..3, thread loads 16B at
    //   row = j*32 + tid/8 , k-chunk = (tid%8)*8 elements
    // which lands at LDS byte offset j*4096 + tid*16 (contiguous in wave order).
    const _Float16* a_src = A  + (long)(brow + (tid >> 3)) * K_TOT + (tid & 7) * 8;
    const _Float16* b_src = Bw + (long)(bcol + (tid >> 3)) * K_TOT + (tid & 7) * 8;
    char* alds = (char*)Als + wave * 1024;   // wave-uniform LDS dest base
    char* blds = (char*)Bls + wave * 1024;

    const int fr   = lane & 15;   // m (A) / n (B) within 16x16 tile
    const int quad = lane >> 4;   // k-chunk selector (quad*8)
    const int wrow = (wave >> 1) * 64;
    const int wcol = (wave & 1) * 64;

    v4f acc[4][4];
#pragma unroll
    for (int i = 0; i < 4; ++i)
#pragma unroll
        for (int j = 0; j < 4; ++j)
            acc[i][j] = (v4f)0.0f;

    // Precompute LDS fragment element offsets (in _Float16 units)
    int a_off[4], b_off[4];
#pragma unroll
    for (int i = 0; i < 4; ++i) {
        a_off[i] = (wrow + i * 16 + fr) * BK + quad * 8;
        b_off[i] = (wcol + i * 16 + fr) * BK + quad * 8;
    }

    for (int kt = 0; kt < K_TOT / BK; ++kt) {
        const _Float16* ak = a_src + kt * BK;
        const _Float16* bk = b_src + kt * BK;
#pragma unroll
        for (int j = 0; j < 4; ++j) {
            load_lds16(ak + j * 32 * K_TOT, alds + j * 4096);
            load_lds16(bk + j * 32 * K_TOT, blds + j * 4096);
        }
        __syncthreads();   // drains vmcnt(0): LDS staged

#pragma unroll
        for (int ks = 0; ks < 2; ++ks) {
            v8h af[4], bf[4];
#pragma unroll
            for (int i = 0; i < 4; ++i)
                af[i] = *(const v8h*)(Als + a_off[i] + ks * 32);
#pragma unroll
            for (int i = 0; i < 4; ++i)
                bf[i] = *(const v8h*)(Bls + b_off[i] + ks * 32);
#pragma unroll
            for (int mi = 0; mi < 4; ++mi)
#pragma unroll
                for (int ni = 0; ni < 4; ++ni)
                    acc[mi][ni] = __builtin_amdgcn_mfma_f32_16x16x32_f16(
                        af[mi], bf[ni], acc[mi][ni], 0, 0, 0);
        }
        __syncthreads();   // all waves done with LDS before next stage
    }

    // Epilogue: C/D layout col = lane&15, row = quad*4 + reg
#pragma unroll
    for (int ni = 0; ni < 4; ++ni) {
        const int n = bcol + wcol + ni * 16 + fr;
        const float sc = w_scale[n];
        const float bi = bias_g[n];
#pragma unroll
        for (int mi = 0; mi < 4; ++mi) {
            const int row0 = brow + wrow + mi * 16 + quad * 4;
            float* cp = C + (long)row0 * N_TOT + n;
#pragma unroll
            for (int r = 0; r < 4; ++r)
                cp[(long)r * N_TOT] = acc[mi][ni][r] * sc + bi;
        }
    }
}

// ---------------------------------------------------------------------------
// Fallback (only if ws_size too small): correct but slow
// ---------------------------------------------------------------------------
__global__ void naive_kernel(const float* __restrict__ in, const int* __restrict__ q,
                             const float* __restrict__ sc, const float* __restrict__ bi,
                             float* __restrict__ out) {
    long idx = (long)blockIdx.x * 256 + threadIdx.x;
    int m = (int)(idx / N_TOT), n = (int)(idx % N_TOT);
    const float* a = in + (long)m * K_TOT;
    const int* w = q + (long)n * K_TOT;
    float s = 0.f;
    for (int k = 0; k < K_TOT; k += 4) {
        s += a[k] * (float)w[k] + a[k + 1] * (float)w[k + 1] +
             a[k + 2] * (float)w[k + 2] + a[k + 3] * (float)w[k + 3];
    }
    out[idx] = s * sc[n] + bi[n];
}

extern "C" void kernel_launch(void* const* d_in, const int* in_sizes, int n_in,
                              void* d_out, int out_size, void* d_ws, size_t ws_size,
                              hipStream_t stream) {
    const float* input   = (const float*)d_in[0];
    const int*   qweight = (const int*)d_in[1];
    const float* w_scale = (const float*)d_in[2];
    // d_in[3] = w_zp (all zeros, symmetric quant -> no-op)
    const float* bias    = (const float*)d_in[4];
    float* out = (float*)d_out;

    const size_t needA = (size_t)M_TOT * K_TOT * sizeof(_Float16);  // 64 MiB
    const size_t needW = (size_t)N_TOT * K_TOT * sizeof(_Float16);  // 86 MiB

    if (ws_size >= needA + needW) {
        _Float16* A16 = (_Float16*)d_ws;
        _Float16* W16 = (_Float16*)((char*)d_ws + needA);

        cvt_a_kernel<<<(M_TOT * (long)K_TOT / 8) / 256, 256, 0, stream>>>(input, A16);
        cvt_w_kernel<<<(N_TOT * (long)K_TOT / 8) / 256, 256, 0, stream>>>(qweight, W16);

        dim3 grid(N_TOT / BN, M_TOT / BM);   // 86 x 64
        qgemm_kernel<<<grid, 256, 0, stream>>>(A16, W16, w_scale, bias, out);
    } else {
        naive_kernel<<<(long)M_TOT * N_TOT / 256, 256, 0, stream>>>(
            input, qweight, w_scale, bias, out);
    }
}